// Round 12
// baseline (106.213 us; speedup 1.0000x reference)
//
#include <hip/hip_runtime.h>

#define NPTS 4096
#define NB   8

typedef __attribute__((ext_vector_type(8)))  short bf16x8;
typedef __attribute__((ext_vector_type(16))) float f32x16;

__device__ __forceinline__ unsigned short bf16_rne(float f) {
    unsigned u = __float_as_uint(f);
    u += 0x7FFFu + ((u >> 16) & 1u);
    return (unsigned short)(u >> 16);
}
__device__ __forceinline__ float bf16_f(unsigned short s) {
    return __uint_as_float(((unsigned)s) << 16);
}

// s(i,j) = ah.bh(3) + al.bh(3) + ah.bl(3) + 1*hh + 1*hl  (11 K-slots of K=16)
// A slots: [ah0,ah1,ah2, al0,al1,al2, ah0,ah1 | ah2, 1, 1, 0,0,0,0,0]
// B slots: [bh0,bh1,bh2, bh0,bh1,bh2, bl0,bl1 | bl2, hh, hl, 0,0,0,0,0]
// (layout + numerics verified on-HW R7/R9/R10/R11: absmax ~0)

// ---------------- pass 0: B fragments only (2 MB) ----------------
__global__ __launch_bounds__(256) void prep_b(
    const float* __restrict__ x, const float* __restrict__ y,
    unsigned short* __restrict__ Bform)
{
    int i   = blockIdx.x * 256 + threadIdx.x;   // 0..65535
    int cid = i >> 12;                          // 0..7: x[b], 8..15: y[b]
    int p   = i & 4095;
    const float* src = (cid < 8) ? x + ((size_t)cid * NPTS + p) * 3
                                 : y + ((size_t)(cid - 8) * NPTS + p) * 3;
    float c0 = src[0], c1 = src[1], c2 = src[2];
    float h  = -0.5f * (c0 * c0 + c1 * c1 + c2 * c2);

    unsigned short h0 = bf16_rne(c0), h1 = bf16_rne(c1), h2 = bf16_rne(c2);
    unsigned short l0 = bf16_rne(c0 - bf16_f(h0));
    unsigned short l1 = bf16_rne(c1 - bf16_f(h1));
    unsigned short l2 = bf16_rne(c2 - bf16_f(h2));
    unsigned short hh = bf16_rne(h);
    unsigned short hl = bf16_rne(h - bf16_f(hh));

    bf16x8 blo, bhi;
    blo[0]=(short)h0; blo[1]=(short)h1; blo[2]=(short)h2; blo[3]=(short)h0;
    blo[4]=(short)h1; blo[5]=(short)h2; blo[6]=(short)l0; blo[7]=(short)l1;
    bhi[0]=(short)l2; bhi[1]=(short)hh; bhi[2]=(short)hl; bhi[3]=0;
    bhi[4]=0; bhi[5]=0; bhi[6]=0; bhi[7]=0;

    int u = p >> 5, pos = p & 31;
    size_t base = ((size_t)cid << 17) + (size_t)u * 1024 + (size_t)pos * 16;
    *(bf16x8*)((char*)Bform + base)       = blo;
    *(bf16x8*)((char*)Bform + base + 512) = bhi;
}

// ---------------- pass 1: fused MFMA chamfer, LDS-staged B ----------------
// grid = 16 clouds * 32 i-chunks = 512 blocks of 256 thr (2 blocks/CU).
// Block loops 8 chunks of 16 B-tiles (16 KB), double-buffered in LDS.
// Wave w owns i-tile iblk*4+w (32 rows); per 2 tiles: 2 ds_read_b128 +
// 2 MFMA + 16 v_max3. LDS pipe is the modeled bottleneck (~6.4 us/CU).
__global__ __launch_bounds__(256, 2) void chamfer_main(
    const float* __restrict__ x, const float* __restrict__ y,
    const unsigned short* __restrict__ Bform,
    float* __restrict__ out)
{
    __shared__ float4 sbuf[2][1024];     // 2 x 16 KB B staging
    __shared__ float  ebuf[4][32 * 33];  // 16.9 KB epilogue (per-wave)

    const int bid  = blockIdx.x;
    const int dirb = bid >> 5;        // 0..15 (A-cloud id)
    const int iblk = bid & 31;        // 0..31 (128 rows each)

    const int tid = threadIdx.x;
    const int w   = tid >> 6;         // wave 0..3
    const int l   = tid & 63;
    const int g   = l >> 5;           // k-half
    const int pos = l & 31;           // row within tile

    const float* Araw = (dirb < 8) ? x + (size_t)dirb * NPTS * 3
                                   : y + (size_t)(dirb - 8) * NPTS * 3;
    const char* Bcloud = (const char*)Bform + ((size_t)(dirb ^ 8) << 17);

    // ---- A fragment in-register from raw floats ----
    bf16x8 afr;
    {
        const float* ap = Araw + (size_t)(iblk * 128 + w * 32 + pos) * 3;
        float c0 = ap[0], c1 = ap[1], c2 = ap[2];
        unsigned short h0 = bf16_rne(c0), h1 = bf16_rne(c1), h2 = bf16_rne(c2);
        unsigned short l0 = bf16_rne(c0 - bf16_f(h0));
        unsigned short l1 = bf16_rne(c1 - bf16_f(h1));
        unsigned short l2 = bf16_rne(c2 - bf16_f(h2));
        const short ONE = (short)0x3F80;
        bf16x8 alo, ahi;
        alo[0]=(short)h0; alo[1]=(short)h1; alo[2]=(short)h2; alo[3]=(short)l0;
        alo[4]=(short)l1; alo[5]=(short)l2; alo[6]=(short)h0; alo[7]=(short)h1;
        ahi[0]=(short)h2; ahi[1]=ONE; ahi[2]=ONE; ahi[3]=0;
        ahi[4]=0; ahi[5]=0; ahi[6]=0; ahi[7]=0;
        #pragma unroll
        for (int e = 0; e < 8; ++e) afr[e] = g ? ahi[e] : alo[e];
    }

    f32x16 zc;
    #pragma unroll
    for (int r = 0; r < 16; ++r) zc[r] = 0.f;

    f32x16 run;
    #pragma unroll
    for (int r = 0; r < 16; ++r) run[r] = -3.0e38f;

    // ---- stage chunk 0 ----
    {
        const float4* g0 = (const float4*)Bcloud;
        #pragma unroll
        for (int r = 0; r < 4; ++r)
            sbuf[0][r * 256 + tid] = g0[r * 256 + tid];
    }
    __syncthreads();

    // ---- 8 chunks x 16 tiles, double-buffered ----
    #pragma unroll 1
    for (int c = 0; c < 8; ++c) {
        const int cur = c & 1;

        float4 st[4];
        if (c < 7) {                       // issue next chunk's global loads
            const float4* gn = (const float4*)(Bcloud + (size_t)(c + 1) * 16384);
            #pragma unroll
            for (int r = 0; r < 4; ++r)
                st[r] = gn[r * 256 + tid];
        }

        #pragma unroll 1
        for (int t = 0; t < 16; t += 2) {
            bf16x8 b0 = *(const bf16x8*)&sbuf[cur][t * 64 + l];
            bf16x8 b1 = *(const bf16x8*)&sbuf[cur][(t + 1) * 64 + l];
            f32x16 d0 = __builtin_amdgcn_mfma_f32_32x32x16_bf16(afr, b0, zc, 0, 0, 0);
            f32x16 d1 = __builtin_amdgcn_mfma_f32_32x32x16_bf16(afr, b1, zc, 0, 0, 0);
            #pragma unroll
            for (int r = 0; r < 16; ++r)
                run[r] = fmaxf(fmaxf(d0[r], d1[r]), run[r]);   // v_max3_f32
        }

        if (c < 7) {
            __syncthreads();               // all reads of the other buffer done
            #pragma unroll
            for (int r = 0; r < 4; ++r)
                sbuf[cur ^ 1][r * 256 + tid] = st[r];
            __syncthreads();               // staging visible before next compute
        }
    }

    // ---- epilogue: row max -> loss, all in-block (verified R11) ----
    #pragma unroll
    for (int r = 0; r < 16; ++r) {
        int rowin = (r & 3) + 8 * (r >> 2) + 4 * g;   // verified C/D map
        ebuf[w][rowin * 33 + pos] = run[r];
    }
    __syncthreads();

    if (l < 32) {
        float m = ebuf[w][l * 33];
        #pragma unroll
        for (int k = 1; k < 32; ++k) m = fmaxf(m, ebuf[w][l * 33 + k]);
        const float* aq = Araw + (size_t)(iblk * 128 + w * 32 + l) * 3;
        float a0 = aq[0], a1 = aq[1], a2 = aq[2];
        float cda = m - 0.5f * (a0 * a0 + a1 * a1 + a2 * a2);
        #pragma unroll
        for (int mask = 16; mask >= 1; mask >>= 1)
            cda += __shfl_xor(cda, mask);
        if (l == 0)
            atomicAdd(out, cda * (-2.0f * 0.005f / 32768.f));
    }
}

extern "C" void kernel_launch(void* const* d_in, const int* in_sizes, int n_in,
                              void* d_out, int out_size, void* d_ws, size_t ws_size,
                              hipStream_t stream) {
    const float* x = (const float*)d_in[0];
    const float* y = (const float*)d_in[1];
    float* out = (float*)d_out;

    unsigned short* Bform = (unsigned short*)d_ws;   // 2 MB

    hipMemsetAsync(out, 0, sizeof(float), stream);
    prep_b<<<dim3(256), dim3(256), 0, stream>>>(x, y, Bform);
    chamfer_main<<<dim3(512), dim3(256), 0, stream>>>(x, y, Bform, out);
}

// Round 13
// 71.473 us; speedup vs baseline: 1.4860x; 1.4860x over previous
//
#include <hip/hip_runtime.h>

#define NPTS 4096
#define NB   8
#define TOT  (2 * NB * NPTS)   // 65536 (i, dir*batch*point) rows

typedef __attribute__((ext_vector_type(8)))  short          bf16x8;
typedef __attribute__((ext_vector_type(8)))  unsigned short u16x8;
typedef __attribute__((ext_vector_type(16))) float          f32x16;

__device__ __forceinline__ unsigned short bf16_rne(float f) {
    unsigned u = __float_as_uint(f);
    u += 0x7FFFu + ((u >> 16) & 1u);
    return (unsigned short)(u >> 16);
}
__device__ __forceinline__ float bf16_f(unsigned short s) {
    return __uint_as_float(((unsigned)s) << 16);
}

// ---------------- pass 0: build fragment-ordered extended bf16 tiles -------
// s(i,j) = ah_i.bh_j + al_i.bh_j + ah_i.bl_j + 1*hh + 1*hl   (11 K-slots)
// (layout + numerics verified on-HW R7/R9/R10/R11/R12: absmax ~0)
__global__ __launch_bounds__(256) void prep_kernel(
    const float* __restrict__ x, const float* __restrict__ y,
    unsigned short* __restrict__ Aform, unsigned short* __restrict__ Bform,
    float* __restrict__ h32, unsigned* __restrict__ smax,
    float* __restrict__ out)
{
    int i   = blockIdx.x * 256 + threadIdx.x;   // 0..65535
    int cid = i >> 12;                          // 0..7: x[b], 8..15: y[b]
    int p   = i & 4095;
    const float* src = (cid < 8) ? x + ((size_t)cid * NPTS + p) * 3
                                 : y + ((size_t)(cid - 8) * NPTS + p) * 3;
    float c0 = src[0], c1 = src[1], c2 = src[2];
    float h  = -0.5f * (c0 * c0 + c1 * c1 + c2 * c2);

    unsigned short h0 = bf16_rne(c0), h1 = bf16_rne(c1), h2 = bf16_rne(c2);
    unsigned short l0 = bf16_rne(c0 - bf16_f(h0));
    unsigned short l1 = bf16_rne(c1 - bf16_f(h1));
    unsigned short l2 = bf16_rne(c2 - bf16_f(h2));
    unsigned short hh = bf16_rne(h);
    unsigned short hl = bf16_rne(h - bf16_f(hh));
    const unsigned short ONE = 0x3F80;

    u16x8 alo, ahi, blo, bhi;
    alo[0]=h0; alo[1]=h1; alo[2]=h2; alo[3]=l0; alo[4]=l1; alo[5]=l2; alo[6]=h0; alo[7]=h1;
    ahi[0]=h2; ahi[1]=ONE; ahi[2]=ONE; ahi[3]=0; ahi[4]=0; ahi[5]=0; ahi[6]=0; ahi[7]=0;
    blo[0]=h0; blo[1]=h1; blo[2]=h2; blo[3]=h0; blo[4]=h1; blo[5]=h2; blo[6]=l0; blo[7]=l1;
    bhi[0]=l2; bhi[1]=hh; bhi[2]=hl; bhi[3]=0; bhi[4]=0; bhi[5]=0; bhi[6]=0; bhi[7]=0;

    int u = p >> 5, pos = p & 31;
    size_t base = ((size_t)cid << 17) + (size_t)u * 1024 + (size_t)pos * 16;
    *(u16x8*)((char*)Aform + base)       = alo;
    *(u16x8*)((char*)Aform + base + 512) = ahi;
    *(u16x8*)((char*)Bform + base)       = blo;
    *(u16x8*)((char*)Bform + base + 512) = bhi;

    h32[i]  = h;     // fp32 h_a for the epilogue (full precision)
    smax[i] = 0u;    // below any order-mapped float
    if (i == 0) *out = 0.f;
}

// ---------------- pass 1: MFMA chamfer core ----------------
// grid = 16 (dir,b) * 8 i-blocks * 4 j-quarters = 512 blocks of 256 thr.
// R13 change vs R9 (best baseline): j-step 4 instead of 2 — 8 iterations
// per wave instead of 16 (empirical: time tracks iteration count, ~600 cyc
// fixed cost each). Two compute passes of 4t x 2j keep worst-case hoisted
// accumulator dests at 8 f32x16 (R9-proven no-spill; R7's 16 spilled).
__global__ __launch_bounds__(256, 2) void chamfer_mfma(
    const unsigned short* __restrict__ Aform,
    const unsigned short* __restrict__ Bform,
    unsigned* __restrict__ smax)
{
    __shared__ float buf[4][64][33];   // 33792 B, per-wave regions

    const int bid  = blockIdx.x;
    const int dirb = bid >> 5;        // 0..15 (A-cloud id)
    const int sub  = bid & 31;
    const int iblk = sub >> 2;        // 0..7
    const int jq   = sub & 3;         // 0..3
    const int bcld = dirb ^ 8;        // B-cloud id (x<->y)

    const int tid = threadIdx.x;
    const int w   = tid >> 6;         // wave 0..3
    const int l   = tid & 63;
    const int g   = l >> 5;           // k-half
    const int pos = l & 31;           // row/col within tile

    const char* Abase = (const char*)Aform + ((size_t)dirb << 17);
    const char* Bbase = (const char*)Bform + ((size_t)bcld << 17);

    // A fragments: i-tiles iblk*16 + w*4 + t (loaded once, reused for all j)
    const int it0 = iblk * 16 + w * 4;
    bf16x8 afr[4];
    #pragma unroll
    for (int t = 0; t < 4; ++t)
        afr[t] = *(const bf16x8*)(Abase + (size_t)(it0 + t) * 1024
                                        + (size_t)g * 512 + (size_t)pos * 16);

    f32x16 zc;
    #pragma unroll
    for (int r = 0; r < 16; ++r) zc[r] = 0.f;

    f32x16 run[4];
    #pragma unroll
    for (int t = 0; t < 4; ++t)
        #pragma unroll
        for (int r = 0; r < 16; ++r) run[t][r] = -3.0e38f;

    const char* Bq = Bbase + (size_t)(jq * 32) * 1024
                           + (size_t)g * 512 + (size_t)pos * 16;

    bf16x8 cb0 = *(const bf16x8*)(Bq);
    bf16x8 cb1 = *(const bf16x8*)(Bq + 1024);
    bf16x8 cb2 = *(const bf16x8*)(Bq + 2048);
    bf16x8 cb3 = *(const bf16x8*)(Bq + 3072);

    #pragma unroll 1
    for (int j = 0; j < 32; j += 4) {
        const int jn = (j + 4) & 31;           // branchless wrap prefetch
        const char* Bn = Bq + (size_t)jn * 1024;
        bf16x8 nb0 = *(const bf16x8*)(Bn);
        bf16x8 nb1 = *(const bf16x8*)(Bn + 1024);
        bf16x8 nb2 = *(const bf16x8*)(Bn + 2048);
        bf16x8 nb3 = *(const bf16x8*)(Bn + 3072);

        // pass A: tiles j, j+1
        #pragma unroll
        for (int t = 0; t < 4; ++t) {
            f32x16 d0 = __builtin_amdgcn_mfma_f32_32x32x16_bf16(afr[t], cb0, zc, 0, 0, 0);
            f32x16 d1 = __builtin_amdgcn_mfma_f32_32x32x16_bf16(afr[t], cb1, zc, 0, 0, 0);
            #pragma unroll
            for (int r = 0; r < 16; ++r)
                run[t][r] = fmaxf(fmaxf(d0[r], d1[r]), run[t][r]);   // v_max3_f32
        }
        // pass B: tiles j+2, j+3
        #pragma unroll
        for (int t = 0; t < 4; ++t) {
            f32x16 d2 = __builtin_amdgcn_mfma_f32_32x32x16_bf16(afr[t], cb2, zc, 0, 0, 0);
            f32x16 d3 = __builtin_amdgcn_mfma_f32_32x32x16_bf16(afr[t], cb3, zc, 0, 0, 0);
            #pragma unroll
            for (int r = 0; r < 16; ++r)
                run[t][r] = fmaxf(fmaxf(d2[r], d3[r]), run[t][r]);   // v_max3_f32
        }
        cb0 = nb0; cb1 = nb1; cb2 = nb2; cb3 = nb3;
    }

    // ---- epilogue, 2 phases of 2 i-tiles each (33 KB LDS) — verified R9 ----
    #pragma unroll
    for (int ph = 0; ph < 2; ++ph) {
        if (ph) __syncthreads();   // phase-1 reads done before overwrite
        #pragma unroll
        for (int tl = 0; tl < 2; ++tl) {
            const int t = 2 * ph + tl;
            #pragma unroll
            for (int r = 0; r < 16; ++r) {
                int rowin = (r & 3) + 8 * (r >> 2) + 4 * g;   // verified C/D map
                buf[w][tl * 32 + rowin][pos] = run[t][r];
            }
        }
        __syncthreads();

        // thread l reduces local row l (stride 33 -> every bank 2-way = free)
        float m = buf[w][l][0];
        #pragma unroll
        for (int k = 1; k < 32; ++k) m = fmaxf(m, buf[w][l][k]);
        int idx = dirb * 4096 + iblk * 512 + w * 128 + 2 * ph * 32 + l;
        unsigned bits = __float_as_uint(m);
        unsigned mu = (bits & 0x80000000u) ? ~bits : (bits | 0x80000000u);
        atomicMax(&smax[idx], mu);
    }
}

// ---------------- pass 2: unmap, add h_a, sum ----------------
__global__ __launch_bounds__(256) void reduce_kernel(
    const unsigned* __restrict__ smax,
    const float* __restrict__ h32,
    float* __restrict__ out)
{
    const int stride = 64 * 256;
    int tid = blockIdx.x * 256 + threadIdx.x;
    float s = 0.f;
    for (int k = tid; k < TOT; k += stride) {
        unsigned u = smax[k];
        unsigned bits = (u & 0x80000000u) ? (u & 0x7FFFFFFFu) : ~u;
        s += __uint_as_float(bits) + h32[k];   // smax + h_a
    }

    #pragma unroll
    for (int off = 32; off > 0; off >>= 1)
        s += __shfl_down(s, off);

    __shared__ float redb[4];
    const int lane = threadIdx.x & 63, wave = threadIdx.x >> 6;
    if (lane == 0) redb[wave] = s;
    __syncthreads();
    if (threadIdx.x == 0) {
        float t = redb[0] + redb[1] + redb[2] + redb[3];
        // min_d = -2*(smax + h_a); loss = 0.005 * sum/32768
        atomicAdd(out, t * (-2.0f * 0.005f / 32768.f));
    }
}

extern "C" void kernel_launch(void* const* d_in, const int* in_sizes, int n_in,
                              void* d_out, int out_size, void* d_ws, size_t ws_size,
                              hipStream_t stream) {
    const float* x = (const float*)d_in[0];
    const float* y = (const float*)d_in[1];
    float* out = (float*)d_out;

    unsigned short* Aform = (unsigned short*)d_ws;                          // 2 MB
    unsigned short* Bform = (unsigned short*)((char*)d_ws + (2u << 20));    // 2 MB
    float*          h32   = (float*)((char*)d_ws + (4u << 20));             // 256 KB
    unsigned*       smax  = (unsigned*)((char*)d_ws + (4u << 20) + (256u << 10));

    prep_kernel<<<dim3(TOT / 256), dim3(256), 0, stream>>>(x, y, Aform, Bform, h32, smax, out);
    chamfer_mfma<<<dim3(512), dim3(256), 0, stream>>>(Aform, Bform, smax);
    reduce_kernel<<<dim3(64), dim3(256), 0, stream>>>(smax, h32, out);
}